// Round 2
// baseline (655.729 us; speedup 1.0000x reference)
//
#include <hip/hip_runtime.h>

#define NUM_HEAD 8
#define D_MODEL  512
#define HEAD_DIM 64
#define NSEQ     2048
// 0.125 * log2(e) — folded into Q at projection time
#define SCALE_LOG2E 0.18033688011112042f

typedef __attribute__((ext_vector_type(8))) short bf16x8;
typedef __attribute__((ext_vector_type(4))) float f32x4;
typedef __attribute__((ext_vector_type(4))) float vf4;

static __device__ __forceinline__ unsigned short f2bf(float f) {
    unsigned u = __builtin_bit_cast(unsigned, f);
    u += 0x7fffu + ((u >> 16) & 1u);   // RNE
    return (unsigned short)(u >> 16);
}
static __device__ __forceinline__ float bf2f(unsigned short h) {
    unsigned u = ((unsigned)h) << 16;
    return __builtin_bit_cast(float, u);
}
static __device__ __forceinline__ unsigned pk2(float a, float b) {
    return (unsigned)f2bf(a) | ((unsigned)f2bf(b) << 16);
}

// ---------------------------------------------------------------------------
// Fused 3-way projection: z=0: Q = (q@Wq^T + bq)*SCALE -> [b,h,n,d]
//                         z=1: K =  k@Wk^T + bk        -> [b,h,n,d]
//                         z=2: V =  v@Wv^T + bv        -> [b,h,d,n]  (transposed!)
// Tile 128(M) x 64(N) x 32(K); 4 waves as 2x2, each wave 64x32 (4x2 mfma frags)
// grid (32, 8, 3) = 768 blocks = 3 blocks/CU.
// ---------------------------------------------------------------------------
#define PSTR 40  // LDS row stride in bf16 elements (32 + 8 pad)

__global__ __launch_bounds__(256) void proj3_kernel(
    const float* __restrict__ Xq, const float* __restrict__ Xk, const float* __restrict__ Xv,
    const float* __restrict__ Wq, const float* __restrict__ Wk, const float* __restrict__ Wv,
    const float* __restrict__ bq, const float* __restrict__ bk, const float* __restrict__ bv,
    unsigned short* __restrict__ Qp, unsigned short* __restrict__ Kp,
    unsigned short* __restrict__ Vt)
{
    __shared__ unsigned short lA[128 * PSTR];
    __shared__ unsigned short lB[64 * PSTR];

    const int z = blockIdx.z;
    const float* X    = (z == 0) ? Xq : (z == 1) ? Xk : Xv;
    const float* W    = (z == 0) ? Wq : (z == 1) ? Wk : Wv;
    const float* bias = (z == 0) ? bq : (z == 1) ? bk : bv;

    const int tid  = threadIdx.x;
    const int lane = tid & 63, wid = tid >> 6;
    const int quad = lane >> 4, l15 = lane & 15;
    const int wm = (wid >> 1) * 64;   // wave m offset in tile
    const int wn = (wid & 1) * 32;    // wave n offset in tile
    const int m0 = blockIdx.x * 128, n0 = blockIdx.y * 64;

    f32x4 acc[4][2];
    const f32x4 zf = {0.f, 0.f, 0.f, 0.f};
#pragma unroll
    for (int mi = 0; mi < 4; mi++)
#pragma unroll
        for (int ni = 0; ni < 2; ni++) acc[mi][ni] = zf;

    const int arow = tid >> 1, akc = (tid & 1) * 16;  // A: 128 rows x 32k
    const int brow = tid >> 2, bkc = (tid & 3) * 8;   // B:  64 rows x 32k

    for (int k0 = 0; k0 < D_MODEL; k0 += 32) {
        // stage A (fp32 -> bf16)
        const float* ap = X + (m0 + arow) * D_MODEL + k0 + akc;
        float4 a0 = *(const float4*)(ap);
        float4 a1 = *(const float4*)(ap + 4);
        float4 a2 = *(const float4*)(ap + 8);
        float4 a3 = *(const float4*)(ap + 12);
        uint4 w0, w1;
        w0.x = pk2(a0.x, a0.y); w0.y = pk2(a0.z, a0.w);
        w0.z = pk2(a1.x, a1.y); w0.w = pk2(a1.z, a1.w);
        w1.x = pk2(a2.x, a2.y); w1.y = pk2(a2.z, a2.w);
        w1.z = pk2(a3.x, a3.y); w1.w = pk2(a3.z, a3.w);
        *(uint4*)&lA[arow * PSTR + akc]     = w0;
        *(uint4*)&lA[arow * PSTR + akc + 8] = w1;
        // stage B (W rows)
        const float* bp = W + (n0 + brow) * D_MODEL + k0 + bkc;
        float4 b0 = *(const float4*)(bp);
        float4 b1 = *(const float4*)(bp + 4);
        uint4 wb;
        wb.x = pk2(b0.x, b0.y); wb.y = pk2(b0.z, b0.w);
        wb.z = pk2(b1.x, b1.y); wb.w = pk2(b1.z, b1.w);
        *(uint4*)&lB[brow * PSTR + bkc] = wb;
        __syncthreads();

        bf16x8 aF[4], bF[2];
#pragma unroll
        for (int mi = 0; mi < 4; mi++)
            aF[mi] = *(const bf16x8*)&lA[(wm + mi * 16 + l15) * PSTR + quad * 8];
#pragma unroll
        for (int ni = 0; ni < 2; ni++)
            bF[ni] = *(const bf16x8*)&lB[(wn + ni * 16 + l15) * PSTR + quad * 8];
#pragma unroll
        for (int mi = 0; mi < 4; mi++)
#pragma unroll
            for (int ni = 0; ni < 2; ni++)
                acc[mi][ni] = __builtin_amdgcn_mfma_f32_16x16x32_bf16(
                    aF[mi], bF[ni], acc[mi][ni], 0, 0, 0);
        __syncthreads();
    }

    // epilogue: add bias, (scale for Q), permute, store bf16
    const float oscale = (z == 0) ? SCALE_LOG2E : 1.0f;
    const float bv0 = bias[n0 + wn + l15];
    const float bv1 = bias[n0 + wn + 16 + l15];
    unsigned short* outp = (z == 0) ? Qp : Kp;  // z==2 handled below
#pragma unroll
    for (int mi = 0; mi < 4; mi++) {
        const int mbase = m0 + wm + mi * 16 + quad * 4;
#pragma unroll
        for (int ni = 0; ni < 2; ni++) {
            const int c = n0 + wn + ni * 16 + l15;
            const int h = c >> 6, d = c & 63;
            const float bb_add = ni ? bv1 : bv0;
#pragma unroll
            for (int r = 0; r < 4; r++) {
                const int mm = mbase + r;
                const int bb = mm >> 11, n = mm & 2047;
                const float val = (acc[mi][ni][r] + bb_add) * oscale;
                if (z < 2)
                    outp[((bb * NUM_HEAD + h) * NSEQ + n) * HEAD_DIM + d] = f2bf(val);
                else
                    Vt[((bb * NUM_HEAD + h) * HEAD_DIM + d) * NSEQ + n] = f2bf(val);
            }
        }
    }
}

// ---------------------------------------------------------------------------
// Extract diagonal of pearson_matrix: diag[bh, k] = pearson[bh, k, k]
// ---------------------------------------------------------------------------
__global__ void diag_kernel(const float* __restrict__ pearson,
                            float* __restrict__ diag)
{
    const int t = blockIdx.x * blockDim.x + threadIdx.x;  // 32768 total
    const int bh = t >> 11, kk = t & 2047;
    diag[t] = __builtin_nontemporal_load(
        pearson + ((size_t)(bh * NSEQ + kk)) * NSEQ + kk);
}

// ---------------------------------------------------------------------------
// Fused flash-style attention — BARRIER-FREE K-loop.
//   Q pre-scaled by SCALING*log2e, so p = exp2(QK^T) directly (|S*scale| small,
//   no max subtraction needed). l += rowsum(p); O += (p*mask*diag) @ V.
// Each wave owns a 16-q strip; its P round-trip through LDS is wave-private
// (writes C-layout rows wid*16..+15, reads same rows in A-layout), and LDS ops
// from one wave execute in order -> no __syncthreads anywhere in the loop.
// V comes pre-transposed (Vt[bh][d][n]) so PV B-frags are direct 16B loads.
// Mask (the 268 MB HBM stream) is read in A-layout: 4x nontemporal dwordx4.
// ---------------------------------------------------------------------------
#define VSTR 68  // 64 + 4: quad-disjoint banks on b16 C-layout writes

__global__ __launch_bounds__(256) void attn_kernel(
    const unsigned short* __restrict__ Qp, const unsigned short* __restrict__ Kp,
    const unsigned short* __restrict__ Vt, const float* __restrict__ diag,
    const float* __restrict__ mask, float* __restrict__ out)
{
    __shared__ unsigned short lP[64 * VSTR];   // wave-private 16-row strips

    const int tid  = threadIdx.x;
    const int lane = tid & 63, wid = tid >> 6;
    const int quad = lane >> 4, l15 = lane & 15;
    const int bh = blockIdx.y;            // b*8 + h
    const int q0 = blockIdx.x * 64;

    const unsigned short* Qb  = Qp + (size_t)bh * NSEQ * HEAD_DIM;
    const unsigned short* Kb  = Kp + (size_t)bh * NSEQ * HEAD_DIM;
    const unsigned short* Vtb = Vt + (size_t)bh * HEAD_DIM * NSEQ;
    const float* mrow  = mask + (size_t)bh * NSEQ * NSEQ
                              + (size_t)(q0 + wid * 16 + l15) * NSEQ + quad * 8;
    const float* diagb = diag + bh * NSEQ + quad * 8;

    // persistent Q fragments (pre-scaled at projection)
    bf16x8 qF[2];
    {
        const unsigned short* qp = Qb + (q0 + wid * 16 + l15) * HEAD_DIM + quad * 8;
        qF[0] = *(const bf16x8*)qp;
        qF[1] = *(const bf16x8*)(qp + 32);
    }

    const f32x4 zf = {0.f, 0.f, 0.f, 0.f};
    f32x4 oacc[4] = {zf, zf, zf, zf};
    float lacc[4] = {0.f, 0.f, 0.f, 0.f};

    const int lpw = (wid * 16 + quad * 4) * VSTR + l15;  // C-layout write base
    const int lpr = (wid * 16 + l15) * VSTR + quad * 8;  // A-layout read base

    for (int kt = 0; kt < NSEQ; kt += 64) {
        // ---- issue ALL global loads up front (compiler schedules vmcnt) ----
        bf16x8 kF[4][2];
#pragma unroll
        for (int nt = 0; nt < 4; nt++) {
            const unsigned short* kp = Kb + (kt + nt * 16 + l15) * HEAD_DIM + quad * 8;
            kF[nt][0] = *(const bf16x8*)kp;
            kF[nt][1] = *(const bf16x8*)(kp + 32);
        }
        bf16x8 vF[2][4];
#pragma unroll
        for (int ks = 0; ks < 2; ks++)
#pragma unroll
            for (int nt = 0; nt < 4; nt++)
                vF[ks][nt] = *(const bf16x8*)&Vtb[(nt * 16 + l15) * NSEQ
                                                  + kt + ks * 32 + quad * 8];
        // mask in A-layout: 8 consecutive floats per lane per ks (nontemporal)
        vf4 mA[4], dA[4];
#pragma unroll
        for (int ks = 0; ks < 2; ks++) {
            mA[2 * ks]     = __builtin_nontemporal_load((const vf4*)(mrow + kt + ks * 32));
            mA[2 * ks + 1] = __builtin_nontemporal_load((const vf4*)(mrow + kt + ks * 32 + 4));
            dA[2 * ks]     = *(const vf4*)(diagb + kt + ks * 32);
            dA[2 * ks + 1] = *(const vf4*)(diagb + kt + ks * 32 + 4);
        }

        // ---- S = Q K^T (16q x 64k strip per wave) ----
        f32x4 sacc[4];
#pragma unroll
        for (int nt = 0; nt < 4; nt++) {
            sacc[nt] = __builtin_amdgcn_mfma_f32_16x16x32_bf16(qF[0], kF[nt][0], zf, 0, 0, 0);
            sacc[nt] = __builtin_amdgcn_mfma_f32_16x16x32_bf16(qF[1], kF[nt][1], sacc[nt], 0, 0, 0);
        }

        // ---- p = exp2(S); accumulate l; p -> LDS (bf16, C-layout) ----
#pragma unroll
        for (int cf = 0; cf < 4; cf++)
#pragma unroll
            for (int r = 0; r < 4; r++) {
                const float p = __builtin_amdgcn_exp2f(sacc[cf][r]);
                lacc[r] += p;
                lP[lpw + r * VSTR + cf * 16] = f2bf(p);
            }

        // ---- A-layout read-back, apply mask*diag, PV mfma ----
#pragma unroll
        for (int ks = 0; ks < 2; ks++) {
            const bf16x8 aP = *(const bf16x8*)&lP[lpr + ks * 32];
            bf16x8 aM;
#pragma unroll
            for (int j = 0; j < 8; j++) {
                const float mj = (j < 4) ? mA[2 * ks][j] : mA[2 * ks + 1][j - 4];
                const float dj = (j < 4) ? dA[2 * ks][j] : dA[2 * ks + 1][j - 4];
                aM[j] = (short)f2bf(bf2f((unsigned short)aP[j]) * mj * dj);
            }
#pragma unroll
            for (int nt = 0; nt < 4; nt++)
                oacc[nt] = __builtin_amdgcn_mfma_f32_16x16x32_bf16(aM, vF[ks][nt], oacc[nt], 0, 0, 0);
        }
    }

    // reduce l across the 16 lanes sharing each q-row
#pragma unroll
    for (int r = 0; r < 4; r++) {
        float v = lacc[r];
        v += __shfl_xor(v, 1);
        v += __shfl_xor(v, 2);
        v += __shfl_xor(v, 4);
        v += __shfl_xor(v, 8);
        lacc[r] = v;
    }

    const int b = bh >> 3, h = bh & 7;
#pragma unroll
    for (int nt = 0; nt < 4; nt++)
#pragma unroll
        for (int r = 0; r < 4; r++) {
            const int qrow = q0 + wid * 16 + quad * 4 + r;
            __builtin_nontemporal_store(
                oacc[nt][r] / lacc[r],
                out + ((size_t)b * NSEQ + qrow) * D_MODEL + h * HEAD_DIM + nt * 16 + l15);
        }
}

// ---------------------------------------------------------------------------
extern "C" void kernel_launch(void* const* d_in, const int* in_sizes, int n_in,
                              void* d_out, int out_size, void* d_ws, size_t ws_size,
                              hipStream_t stream) {
    const float* q       = (const float*)d_in[0];
    const float* k       = (const float*)d_in[1];
    const float* v       = (const float*)d_in[2];
    const float* mask    = (const float*)d_in[3];
    const float* pearson = (const float*)d_in[4];
    const float* Wq      = (const float*)d_in[5];
    const float* bq      = (const float*)d_in[6];
    const float* Wk      = (const float*)d_in[7];
    const float* bk      = (const float*)d_in[8];
    const float* Wv      = (const float*)d_in[9];
    const float* bv      = (const float*)d_in[10];

    // ws layout: Qp (4 MB) | Kp (4 MB) | Vt (4 MB) | diag (128 KB)
    unsigned short* Qp = (unsigned short*)d_ws;
    unsigned short* Kp = Qp + 2097152;
    unsigned short* Vtp = Kp + 2097152;
    float* diag = (float*)((char*)d_ws + 12582912);
    float* out = (float*)d_out;

    proj3_kernel<<<dim3(32, 8, 3), 256, 0, stream>>>(q, k, v, Wq, Wk, Wv,
                                                     bq, bk, bv, Qp, Kp, Vtp);
    diag_kernel<<<dim3(128), 256, 0, stream>>>(pearson, diag);
    attn_kernel<<<dim3(32, 16), 256, 0, stream>>>(Qp, Kp, Vtp, diag, mask, out);
}

// Round 3
// 628.393 us; speedup vs baseline: 1.0435x; 1.0435x over previous
//
#include <hip/hip_runtime.h>

#define NUM_HEAD 8
#define D_MODEL  512
#define HEAD_DIM 64
#define NSEQ     2048
// 0.125 * log2(e) — folded into Q at projection time
#define SCALE_LOG2E 0.18033688011112042f

typedef __attribute__((ext_vector_type(8))) short bf16x8;
typedef __attribute__((ext_vector_type(4))) float f32x4;
typedef __attribute__((ext_vector_type(4))) float vf4;

static __device__ __forceinline__ unsigned short f2bf(float f) {
    unsigned u = __builtin_bit_cast(unsigned, f);
    u += 0x7fffu + ((u >> 16) & 1u);   // RNE
    return (unsigned short)(u >> 16);
}
static __device__ __forceinline__ float bf2f(unsigned short h) {
    unsigned u = ((unsigned)h) << 16;
    return __builtin_bit_cast(float, u);
}
static __device__ __forceinline__ unsigned pk2(float a, float b) {
    return (unsigned)f2bf(a) | ((unsigned)f2bf(b) << 16);
}

// ---------------------------------------------------------------------------
// Fused 3-way projection: z=0: Q = (q@Wq^T + bq)*SCALE -> [b,h,n,d]
//                         z=1: K =  k@Wk^T + bk        -> [b,h,n,d]
//                         z=2: V =  v@Wv^T + bv        -> [b,h,d,n]  (transposed)
// Tile 128(M) x 64(N) x 64(K): 8 K-steps (2 barriers each), 12 independent
// 16B staging loads per thread per step. (256,2): keep loads in VGPRs.
// ---------------------------------------------------------------------------
#define PSTR 72  // LDS row stride in bf16 elements (64 + 8 pad)

__global__ __launch_bounds__(256, 2) void proj3_kernel(
    const float* __restrict__ Xq, const float* __restrict__ Xk, const float* __restrict__ Xv,
    const float* __restrict__ Wq, const float* __restrict__ Wk, const float* __restrict__ Wv,
    const float* __restrict__ bq, const float* __restrict__ bk, const float* __restrict__ bv,
    unsigned short* __restrict__ Qp, unsigned short* __restrict__ Kp,
    unsigned short* __restrict__ Vt)
{
    __shared__ unsigned short lA[128 * PSTR];
    __shared__ unsigned short lB[64 * PSTR];

    const int z = blockIdx.z;
    const float* X    = (z == 0) ? Xq : (z == 1) ? Xk : Xv;
    const float* W    = (z == 0) ? Wq : (z == 1) ? Wk : Wv;
    const float* bias = (z == 0) ? bq : (z == 1) ? bk : bv;

    const int tid  = threadIdx.x;
    const int lane = tid & 63, wid = tid >> 6;
    const int quad = lane >> 4, l15 = lane & 15;
    const int wm = (wid >> 1) * 64;   // wave m offset in tile
    const int wn = (wid & 1) * 32;    // wave n offset in tile
    const int m0 = blockIdx.x * 128, n0 = blockIdx.y * 64;

    f32x4 acc[4][2];
    const f32x4 zf = {0.f, 0.f, 0.f, 0.f};
#pragma unroll
    for (int mi = 0; mi < 4; mi++)
#pragma unroll
        for (int ni = 0; ni < 2; ni++) acc[mi][ni] = zf;

    const int arow = tid >> 1, akc = (tid & 1) * 32;  // A: 128 rows x 64k, 32 f/thread
    const int brow = tid >> 2, bkc = (tid & 3) * 16;  // B:  64 rows x 64k, 16 f/thread

    for (int k0 = 0; k0 < D_MODEL; k0 += 64) {
        // stage A (fp32 -> bf16): 8 independent float4 loads
        const float* ap = X + (m0 + arow) * D_MODEL + k0 + akc;
        float4 av[8];
#pragma unroll
        for (int i = 0; i < 8; i++) av[i] = *(const float4*)(ap + 4 * i);
        // stage B: 4 independent float4 loads
        const float* bp = W + (n0 + brow) * D_MODEL + k0 + bkc;
        float4 bvv[4];
#pragma unroll
        for (int i = 0; i < 4; i++) bvv[i] = *(const float4*)(bp + 4 * i);

#pragma unroll
        for (int i = 0; i < 4; i++) {
            uint4 w;
            w.x = pk2(av[2 * i].x, av[2 * i].y);
            w.y = pk2(av[2 * i].z, av[2 * i].w);
            w.z = pk2(av[2 * i + 1].x, av[2 * i + 1].y);
            w.w = pk2(av[2 * i + 1].z, av[2 * i + 1].w);
            *(uint4*)&lA[arow * PSTR + akc + 8 * i] = w;
        }
#pragma unroll
        for (int i = 0; i < 2; i++) {
            uint4 w;
            w.x = pk2(bvv[2 * i].x, bvv[2 * i].y);
            w.y = pk2(bvv[2 * i].z, bvv[2 * i].w);
            w.z = pk2(bvv[2 * i + 1].x, bvv[2 * i + 1].y);
            w.w = pk2(bvv[2 * i + 1].z, bvv[2 * i + 1].w);
            *(uint4*)&lB[brow * PSTR + bkc + 8 * i] = w;
        }
        __syncthreads();

#pragma unroll
        for (int ks = 0; ks < 2; ks++) {
            bf16x8 aF[4], bF[2];
#pragma unroll
            for (int mi = 0; mi < 4; mi++)
                aF[mi] = *(const bf16x8*)&lA[(wm + mi * 16 + l15) * PSTR + ks * 32 + quad * 8];
#pragma unroll
            for (int ni = 0; ni < 2; ni++)
                bF[ni] = *(const bf16x8*)&lB[(wn + ni * 16 + l15) * PSTR + ks * 32 + quad * 8];
#pragma unroll
            for (int mi = 0; mi < 4; mi++)
#pragma unroll
                for (int ni = 0; ni < 2; ni++)
                    acc[mi][ni] = __builtin_amdgcn_mfma_f32_16x16x32_bf16(
                        aF[mi], bF[ni], acc[mi][ni], 0, 0, 0);
        }
        __syncthreads();
    }

    // epilogue: add bias, (scale for Q), permute, store bf16
    const float oscale = (z == 0) ? SCALE_LOG2E : 1.0f;
    const float bv0 = bias[n0 + wn + l15];
    const float bv1 = bias[n0 + wn + 16 + l15];
    unsigned short* outp = (z == 0) ? Qp : Kp;  // z==2 handled below
#pragma unroll
    for (int mi = 0; mi < 4; mi++) {
        const int mbase = m0 + wm + mi * 16 + quad * 4;
#pragma unroll
        for (int ni = 0; ni < 2; ni++) {
            const int c = n0 + wn + ni * 16 + l15;
            const int h = c >> 6, d = c & 63;
            const float bb_add = ni ? bv1 : bv0;
#pragma unroll
            for (int r = 0; r < 4; r++) {
                const int mm = mbase + r;
                const int bb = mm >> 11, n = mm & 2047;
                const float val = (acc[mi][ni][r] + bb_add) * oscale;
                if (z < 2)
                    outp[((bb * NUM_HEAD + h) * NSEQ + n) * HEAD_DIM + d] = f2bf(val);
                else
                    Vt[((bb * NUM_HEAD + h) * HEAD_DIM + d) * NSEQ + n] = f2bf(val);
            }
        }
    }
}

// ---------------------------------------------------------------------------
// Extract diagonal of pearson_matrix: diag[bh, k] = pearson[bh, k, k]
// ---------------------------------------------------------------------------
__global__ void diag_kernel(const float* __restrict__ pearson,
                            float* __restrict__ diag)
{
    const int t = blockIdx.x * blockDim.x + threadIdx.x;  // 32768 total
    const int bh = t >> 11, kk = t & 2047;
    diag[t] = __builtin_nontemporal_load(
        pearson + ((size_t)(bh * NSEQ + kk)) * NSEQ + kk);
}

// ---------------------------------------------------------------------------
// Fused flash-style attention — barrier-free K-loop + explicit 2-deep
// register pipeline (prefetch tile t+1 while computing tile t).
// __launch_bounds__(256,2): ~224 VGPR budget so the prefetch actually stays
// in registers (R2 failed because the allocator squeezed to 52 VGPRs and
// serialized every load).
// ---------------------------------------------------------------------------
#define VSTR 68  // 64 + 4: quad-disjoint banks on b16 C-layout writes

__device__ __forceinline__ void load_tile(
    const unsigned short* __restrict__ Kb, const unsigned short* __restrict__ Vtb,
    const float* __restrict__ mrow, int kt, int l15, int quad,
    bf16x8 (&kF)[4][2], bf16x8 (&vF)[2][4], vf4 (&mA)[4])
{
#pragma unroll
    for (int nt = 0; nt < 4; nt++) {
        const unsigned short* kp = Kb + (kt + nt * 16 + l15) * HEAD_DIM + quad * 8;
        kF[nt][0] = *(const bf16x8*)kp;
        kF[nt][1] = *(const bf16x8*)(kp + 32);
    }
#pragma unroll
    for (int ks = 0; ks < 2; ks++)
#pragma unroll
        for (int nt = 0; nt < 4; nt++)
            vF[ks][nt] = *(const bf16x8*)&Vtb[(nt * 16 + l15) * NSEQ
                                              + kt + ks * 32 + quad * 8];
#pragma unroll
    for (int ks = 0; ks < 2; ks++) {
        mA[2 * ks]     = __builtin_nontemporal_load((const vf4*)(mrow + kt + ks * 32));
        mA[2 * ks + 1] = __builtin_nontemporal_load((const vf4*)(mrow + kt + ks * 32 + 4));
    }
}

__device__ __forceinline__ void compute_tile(
    const bf16x8 (&qF)[2], const bf16x8 (&kF)[4][2], const bf16x8 (&vF)[2][4],
    const vf4 (&mA)[4], const float* __restrict__ diagb, int kt,
    unsigned short* lP, int lpw, int lpr,
    f32x4 (&oacc)[4], float (&lacc)[4])
{
    const f32x4 zf = {0.f, 0.f, 0.f, 0.f};
    // diag JIT (tiny, L1-resident) — issue before the MFMA chain
    vf4 dA[4];
#pragma unroll
    for (int ks = 0; ks < 2; ks++) {
        dA[2 * ks]     = *(const vf4*)(diagb + kt + ks * 32);
        dA[2 * ks + 1] = *(const vf4*)(diagb + kt + ks * 32 + 4);
    }

    // S = Q K^T (16q x 64k strip per wave)
    f32x4 sacc[4];
#pragma unroll
    for (int nt = 0; nt < 4; nt++) {
        sacc[nt] = __builtin_amdgcn_mfma_f32_16x16x32_bf16(qF[0], kF[nt][0], zf, 0, 0, 0);
        sacc[nt] = __builtin_amdgcn_mfma_f32_16x16x32_bf16(qF[1], kF[nt][1], sacc[nt], 0, 0, 0);
    }

    // p = exp2(S); accumulate l; p -> LDS (bf16, C-layout, wave-private rows)
#pragma unroll
    for (int cf = 0; cf < 4; cf++)
#pragma unroll
        for (int r = 0; r < 4; r++) {
            const float p = __builtin_amdgcn_exp2f(sacc[cf][r]);
            lacc[r] += p;
            lP[lpw + r * VSTR + cf * 16] = f2bf(p);
        }

    // A-layout read-back, apply mask*diag, PV mfma
#pragma unroll
    for (int ks = 0; ks < 2; ks++) {
        const bf16x8 aP = *(const bf16x8*)&lP[lpr + ks * 32];
        bf16x8 aM;
#pragma unroll
        for (int j = 0; j < 8; j++) {
            const float mj = (j < 4) ? mA[2 * ks][j] : mA[2 * ks + 1][j - 4];
            const float dj = (j < 4) ? dA[2 * ks][j] : dA[2 * ks + 1][j - 4];
            aM[j] = (short)f2bf(bf2f((unsigned short)aP[j]) * mj * dj);
        }
#pragma unroll
        for (int nt = 0; nt < 4; nt++)
            oacc[nt] = __builtin_amdgcn_mfma_f32_16x16x32_bf16(aM, vF[ks][nt], oacc[nt], 0, 0, 0);
    }
}

__global__ __launch_bounds__(256, 2) void attn_kernel(
    const unsigned short* __restrict__ Qp, const unsigned short* __restrict__ Kp,
    const unsigned short* __restrict__ Vt, const float* __restrict__ diag,
    const float* __restrict__ mask, float* __restrict__ out)
{
    __shared__ unsigned short lP[64 * VSTR];   // wave-private 16-row strips

    const int tid  = threadIdx.x;
    const int lane = tid & 63, wid = tid >> 6;
    const int quad = lane >> 4, l15 = lane & 15;
    const int bh = blockIdx.y;            // b*8 + h
    const int q0 = blockIdx.x * 64;

    const unsigned short* Qb  = Qp + (size_t)bh * NSEQ * HEAD_DIM;
    const unsigned short* Kb  = Kp + (size_t)bh * NSEQ * HEAD_DIM;
    const unsigned short* Vtb = Vt + (size_t)bh * HEAD_DIM * NSEQ;
    const float* mrow  = mask + (size_t)bh * NSEQ * NSEQ
                              + (size_t)(q0 + wid * 16 + l15) * NSEQ + quad * 8;
    const float* diagb = diag + bh * NSEQ + quad * 8;

    // persistent Q fragments (pre-scaled at projection)
    bf16x8 qF[2];
    {
        const unsigned short* qp = Qb + (q0 + wid * 16 + l15) * HEAD_DIM + quad * 8;
        qF[0] = *(const bf16x8*)qp;
        qF[1] = *(const bf16x8*)(qp + 32);
    }

    const f32x4 zf = {0.f, 0.f, 0.f, 0.f};
    f32x4 oacc[4] = {zf, zf, zf, zf};
    float lacc[4] = {0.f, 0.f, 0.f, 0.f};

    const int lpw = (wid * 16 + quad * 4) * VSTR + l15;  // C-layout write base
    const int lpr = (wid * 16 + l15) * VSTR + quad * 8;  // A-layout read base

    // -------- 2-deep register pipeline over 32 K-tiles (unroll by 2) --------
    bf16x8 kF0[4][2], kF1[4][2];
    bf16x8 vF0[2][4], vF1[2][4];
    vf4 mA0[4], mA1[4];

    load_tile(Kb, Vtb, mrow, 0, l15, quad, kF0, vF0, mA0);

    for (int kt = 0; kt < NSEQ; kt += 128) {
        load_tile(Kb, Vtb, mrow, kt + 64, l15, quad, kF1, vF1, mA1);
        compute_tile(qF, kF0, vF0, mA0, diagb, kt, lP, lpw, lpr, oacc, lacc);
        const int ktn = (kt + 128) & (NSEQ - 1);   // wrap OOB prefetch (unused)
        load_tile(Kb, Vtb, mrow, ktn, l15, quad, kF0, vF0, mA0);
        compute_tile(qF, kF1, vF1, mA1, diagb, kt + 64, lP, lpw, lpr, oacc, lacc);
    }

    // reduce l across the 16 lanes sharing each q-row
#pragma unroll
    for (int r = 0; r < 4; r++) {
        float v = lacc[r];
        v += __shfl_xor(v, 1);
        v += __shfl_xor(v, 2);
        v += __shfl_xor(v, 4);
        v += __shfl_xor(v, 8);
        lacc[r] = v;
    }

    const int b = bh >> 3, h = bh & 7;
#pragma unroll
    for (int nt = 0; nt < 4; nt++)
#pragma unroll
        for (int r = 0; r < 4; r++) {
            const int qrow = q0 + wid * 16 + quad * 4 + r;
            __builtin_nontemporal_store(
                oacc[nt][r] / lacc[r],
                out + ((size_t)b * NSEQ + qrow) * D_MODEL + h * HEAD_DIM + nt * 16 + l15);
        }
}

// ---------------------------------------------------------------------------
extern "C" void kernel_launch(void* const* d_in, const int* in_sizes, int n_in,
                              void* d_out, int out_size, void* d_ws, size_t ws_size,
                              hipStream_t stream) {
    const float* q       = (const float*)d_in[0];
    const float* k       = (const float*)d_in[1];
    const float* v       = (const float*)d_in[2];
    const float* mask    = (const float*)d_in[3];
    const float* pearson = (const float*)d_in[4];
    const float* Wq      = (const float*)d_in[5];
    const float* bq      = (const float*)d_in[6];
    const float* Wk      = (const float*)d_in[7];
    const float* bk      = (const float*)d_in[8];
    const float* Wv      = (const float*)d_in[9];
    const float* bv      = (const float*)d_in[10];

    // ws layout: Qp (4 MB) | Kp (4 MB) | Vt (4 MB) | diag (128 KB)
    unsigned short* Qp = (unsigned short*)d_ws;
    unsigned short* Kp = Qp + 2097152;
    unsigned short* Vtp = Kp + 2097152;
    float* diag = (float*)((char*)d_ws + 12582912);
    float* out = (float*)d_out;

    proj3_kernel<<<dim3(32, 8, 3), 256, 0, stream>>>(q, k, v, Wq, Wk, Wv,
                                                     bq, bk, bv, Qp, Kp, Vtp);
    diag_kernel<<<dim3(128), 256, 0, stream>>>(pearson, diag);
    attn_kernel<<<dim3(32, 16), 256, 0, stream>>>(Qp, Kp, Vtp, diag, mask, out);
}